// Round 13
// baseline (148.136 us; speedup 1.0000x reference)
//
#include <hip/hip_runtime.h>
#include <hip/hip_bf16.h>
#include <math.h>

// QuantumFFN: out[m,n] = sum_k relu(sum_q cos(x[m,q])cos(theta[q]) * W1[k,q]) * W2[n,k]
// M=16384, N=1024, K=4096, Q=8.
//
// r13 = r12 champion + (a) STAGE hoisted to top of tile, (b) 3-group read/MFMA ladder
//   with counted lgkm(8)/(4)/(0). Everything else identical.
// Pass 1 (k_prep): h -> bf16 tiles [mt 64][kt 128][256r][32k], W2 -> [nt 8][kt 128][128r][32k],
//   64-B rows pre-swizzled with SWZ32 (zero conflicts, rounds 3-12).
// Pass 2 (k_gemm): BM=256 BN=128 BK=32, 256 thr (4 waves, wave=128x64), ring-3 LDS
//   (72 KB -> 2 blocks/CU), counted vmcnt(6), 1 barrier per K-tile, XCD map XCD=mt&7.

using f32x4  = __attribute__((ext_vector_type(4))) float;
using bf16x8 = __attribute__((ext_vector_type(8))) short;
using i32x4  = __attribute__((ext_vector_type(4))) int;

#define M_TOT 16384
#define N_TOT 1024
#define K_TOT 4096
#define NKT   128        // K-tiles of 32
#define ATB   16384      // A tile: 256 rows x 32 k x 2B
#define BTB   8192       // B tile: 128 rows x 32 k x 2B

static const size_t H_BYTES   = (size_t)M_TOT * K_TOT * 2;   // 128 MiB
static const size_t W2B_BYTES = (size_t)N_TOT * K_TOT * 2;   //   8 MiB
static const size_t WS_NEED   = H_BYTES + W2B_BYTES;

// swizzle within a 64-byte tile row (4 slots of 16B): slot' = slot ^ ((row>>1)&3)
#define SWZ32(row, bytecol) ((bytecol) ^ ((((row) >> 1) & 3) << 4))

#define GLD16(gp, lp) __builtin_amdgcn_global_load_lds( \
    (const __attribute__((address_space(1))) unsigned int*)(const void*)(gp), \
    (__attribute__((address_space(3))) unsigned int*)(void*)(lp), 16, 0, 0)

static __device__ inline unsigned short f2bf(float f) {
    __hip_bfloat16 b = __float2bfloat16(f);
    unsigned short u;
    __builtin_memcpy(&u, &b, 2);
    return u;
}

// ---------------- pass 1: h and W2 -> bf16 tiles, SWZ32 pre-swizzled ----------------
__global__ __launch_bounds__(256)
void k_prep(const float* __restrict__ x, const float* __restrict__ theta,
            const float* __restrict__ W1, const float* __restrict__ W2,
            char* __restrict__ hws, char* __restrict__ w2ws)
{
    __shared__ float sZ[256 * 8];
    __shared__ float sW[128 * 8];
    const int tid = threadIdx.x;

    if (blockIdx.x < 2048) {
        const int bx = blockIdx.x >> 5;
        const int by = blockIdx.x & 31;

        {   // z for this block's 256 rows (one row per thread)
            const float* xp = x + ((size_t)bx * 256 + tid) * 1024;
            f32x4 a = *reinterpret_cast<const f32x4*>(xp);
            f32x4 b = *reinterpret_cast<const f32x4*>(xp + 4);
            #pragma unroll
            for (int q = 0; q < 4; ++q) {
                sZ[tid * 8 + q]     = cosf(a[q]) * cosf(theta[q]);
                sZ[tid * 8 + 4 + q] = cosf(b[q]) * cosf(theta[q + 4]);
            }
        }
        *reinterpret_cast<f32x4*>(&sW[tid * 4]) =
            *reinterpret_cast<const f32x4*>(W1 + (size_t)by * 1024 + tid * 4);
        __syncthreads();

        const int tm = tid >> 4;     // rows tm*16..+15
        const int tk = tid & 15;     // k-cols tk*8..+7 (within 128-chunk)

        f32x4 wA[8], wB[8];
        #pragma unroll
        for (int kk = 0; kk < 8; ++kk) {
            wA[kk] = *reinterpret_cast<const f32x4*>(&sW[(tk * 8 + kk) * 8]);
            wB[kk] = *reinterpret_cast<const f32x4*>(&sW[(tk * 8 + kk) * 8 + 4]);
        }

        const int kt = by * 4 + (tk >> 2);   // global K-tile (32 k), 0..127
        const int slotb = (tk & 3) * 16;     // 16B slot within 64-B tile row
        char* tb = hws + ((size_t)(bx * NKT + kt)) * ATB;

        #pragma unroll
        for (int i = 0; i < 16; ++i) {
            const int R = tm * 16 + i;       // 0..255
            f32x4 za = *reinterpret_cast<const f32x4*>(&sZ[R * 8]);
            f32x4 zb = *reinterpret_cast<const f32x4*>(&sZ[R * 8 + 4]);
            unsigned hu[8];
            #pragma unroll
            for (int kk = 0; kk < 8; ++kk) {
                float h = 0.f;
                #pragma unroll
                for (int q = 0; q < 4; ++q) {
                    h = fmaf(za[q], wA[kk][q], h);
                    h = fmaf(zb[q], wB[kk][q], h);
                }
                hu[kk] = (unsigned)f2bf(fmaxf(h, 0.f));
            }
            i32x4 pk;
            pk[0] = (int)(hu[0] | (hu[1] << 16));
            pk[1] = (int)(hu[2] | (hu[3] << 16));
            pk[2] = (int)(hu[4] | (hu[5] << 16));
            pk[3] = (int)(hu[6] | (hu[7] << 16));
            *reinterpret_cast<i32x4*>(tb + R * 64 + SWZ32(R, slotb)) = pk;
        }
    } else {
        const int gt = (blockIdx.x - 2048) * 256 + tid;  // one 8-k (16B) unit each
        const int n  = gt >> 9;                          // 512 units per n-row
        const int k8 = gt & 511;
        const float* p = W2 + (size_t)n * K_TOT + k8 * 8;
        f32x4 a = *reinterpret_cast<const f32x4*>(p);
        f32x4 b = *reinterpret_cast<const f32x4*>(p + 4);
        i32x4 pk;
        pk[0] = (int)((unsigned)f2bf(a[0]) | ((unsigned)f2bf(a[1]) << 16));
        pk[1] = (int)((unsigned)f2bf(a[2]) | ((unsigned)f2bf(a[3]) << 16));
        pk[2] = (int)((unsigned)f2bf(b[0]) | ((unsigned)f2bf(b[1]) << 16));
        pk[3] = (int)((unsigned)f2bf(b[2]) | ((unsigned)f2bf(b[3]) << 16));
        const int nt = n >> 7, r = n & 127, kt = k8 >> 2, slotb = (k8 & 3) * 16;
        char* dst = w2ws + ((size_t)(nt * NKT + kt)) * BTB + r * 64 + SWZ32(r, slotb);
        *reinterpret_cast<i32x4*>(dst) = pk;
    }
}

// ---------------- pass 2: out = h @ W2^T ----------------
// ring-3 LDS: slot r at r*24576 (A 16 KB + B 8 KB). Stage tile t+2 at TOP of tile t.
// Per tile: stage 6 GLD -> reads G1[b0,b1,a0,a1] G2[b2,b3,a2,a3] G3[a4..7] ->
// lgkm(8) -> 4 MFMA -> lgkm(4) -> 12 MFMA -> lgkm(0) -> 16 MFMA -> vmcnt(6) -> s_barrier.

#define STAGE_T(T, RB2) do {                                              \
    const char* ga_ = aT + (size_t)(T) * ATB;                             \
    const char* gb_ = bT + (size_t)(T) * BTB;                             \
    char* la_ = lds + (RB2) * 24576;                                      \
    GLD16(ga_ + tid * 16,         la_ + tid * 16);                        \
    GLD16(ga_ + 4096 + tid * 16,  la_ + 4096 + tid * 16);                 \
    GLD16(ga_ + 8192 + tid * 16,  la_ + 8192 + tid * 16);                 \
    GLD16(ga_ + 12288 + tid * 16, la_ + 12288 + tid * 16);                \
    GLD16(gb_ + tid * 16,         la_ + 16384 + tid * 16);                \
    GLD16(gb_ + 4096 + tid * 16,  la_ + 16384 + 4096 + tid * 16);         \
} while (0)

#define TILE(RB, T, DOSTAGE, WN) do {                                     \
    const char* sa_ = lds + (RB) * 24576;                                 \
    const char* sb_ = sa_ + 16384;                                        \
    if (DOSTAGE) STAGE_T((T) + 2, ((RB) + 2) % 3);                        \
    __builtin_amdgcn_sched_barrier(0);                                    \
    bf16x8 af[8], bfr[4];                                                 \
    /* G1 */                                                              \
    bfr[0] = *reinterpret_cast<const bf16x8*>(sb_ + boff[0]);             \
    bfr[1] = *reinterpret_cast<const bf16x8*>(sb_ + boff[1]);             \
    af[0]  = *reinterpret_cast<const bf16x8*>(sa_ + aoff[0]);             \
    af[1]  = *reinterpret_cast<const bf16x8*>(sa_ + aoff[1]);             \
    __builtin_amdgcn_sched_barrier(0);                                    \
    /* G2 */                                                              \
    bfr[2] = *reinterpret_cast<const bf16x8*>(sb_ + boff[2]);             \
    bfr[3] = *reinterpret_cast<const bf16x8*>(sb_ + boff[3]);             \
    af[2]  = *reinterpret_cast<const bf16x8*>(sa_ + aoff[2]);             \
    af[3]  = *reinterpret_cast<const bf16x8*>(sa_ + aoff[3]);             \
    __builtin_amdgcn_sched_barrier(0);                                    \
    /* G3 */                                                              \
    af[4]  = *reinterpret_cast<const bf16x8*>(sa_ + aoff[4]);             \
    af[5]  = *reinterpret_cast<const bf16x8*>(sa_ + aoff[5]);             \
    af[6]  = *reinterpret_cast<const bf16x8*>(sa_ + aoff[6]);             \
    af[7]  = *reinterpret_cast<const bf16x8*>(sa_ + aoff[7]);             \
    asm volatile("s_waitcnt lgkmcnt(8)" ::: "memory");                    \
    __builtin_amdgcn_sched_barrier(0);                                    \
    __builtin_amdgcn_s_setprio(1);                                        \
    _Pragma("unroll")                                                     \
    for (int i = 0; i < 2; ++i)                                           \
        _Pragma("unroll")                                                 \
        for (int j = 0; j < 2; ++j)                                       \
            acc[i][j] = __builtin_amdgcn_mfma_f32_16x16x32_bf16(af[i], bfr[j], acc[i][j], 0, 0, 0); \
    __builtin_amdgcn_s_setprio(0);                                        \
    asm volatile("s_waitcnt lgkmcnt(4)" ::: "memory");                    \
    __builtin_amdgcn_sched_barrier(0);                                    \
    __builtin_amdgcn_s_setprio(1);                                        \
    _Pragma("unroll")                                                     \
    for (int i = 0; i < 2; ++i)                                           \
        _Pragma("unroll")                                                 \
        for (int j = 2; j < 4; ++j)                                       \
            acc[i][j] = __builtin_amdgcn_mfma_f32_16x16x32_bf16(af[i], bfr[j], acc[i][j], 0, 0, 0); \
    _Pragma("unroll")                                                     \
    for (int i = 2; i < 4; ++i)                                           \
        _Pragma("unroll")                                                 \
        for (int j = 0; j < 4; ++j)                                       \
            acc[i][j] = __builtin_amdgcn_mfma_f32_16x16x32_bf16(af[i], bfr[j], acc[i][j], 0, 0, 0); \
    __builtin_amdgcn_s_setprio(0);                                        \
    asm volatile("s_waitcnt lgkmcnt(0)" ::: "memory");                    \
    __builtin_amdgcn_sched_barrier(0);                                    \
    __builtin_amdgcn_s_setprio(1);                                        \
    _Pragma("unroll")                                                     \
    for (int i = 4; i < 8; ++i)                                           \
        _Pragma("unroll")                                                 \
        for (int j = 0; j < 4; ++j)                                       \
            acc[i][j] = __builtin_amdgcn_mfma_f32_16x16x32_bf16(af[i], bfr[j], acc[i][j], 0, 0, 0); \
    __builtin_amdgcn_s_setprio(0);                                        \
    asm volatile("s_waitcnt vmcnt(" #WN ")" ::: "memory");                \
    __builtin_amdgcn_sched_barrier(0);                                    \
    __builtin_amdgcn_s_barrier();                                         \
    __builtin_amdgcn_sched_barrier(0);                                    \
} while (0)

#define TILE_LAST(RB) do {                                                \
    const char* sa_ = lds + (RB) * 24576;                                 \
    const char* sb_ = sa_ + 16384;                                        \
    bf16x8 af[8], bfr[4];                                                 \
    _Pragma("unroll")                                                     \
    for (int i = 0; i < 8; ++i)                                           \
        af[i] = *reinterpret_cast<const bf16x8*>(sa_ + aoff[i]);          \
    _Pragma("unroll")                                                     \
    for (int j = 0; j < 4; ++j)                                           \
        bfr[j] = *reinterpret_cast<const bf16x8*>(sb_ + boff[j]);         \
    asm volatile("s_waitcnt lgkmcnt(0)" ::: "memory");                    \
    __builtin_amdgcn_sched_barrier(0);                                    \
    _Pragma("unroll")                                                     \
    for (int i = 0; i < 8; ++i)                                           \
        _Pragma("unroll")                                                 \
        for (int j = 0; j < 4; ++j)                                       \
            acc[i][j] = __builtin_amdgcn_mfma_f32_16x16x32_bf16(af[i], bfr[j], acc[i][j], 0, 0, 0); \
} while (0)

__global__ __launch_bounds__(256, 2)
void k_gemm(const char* __restrict__ hws, const char* __restrict__ w2ws,
            float* __restrict__ out)
{
    __shared__ __align__(16) char lds[73728];   // 3 x (16K A + 8K B)

    const int tid  = threadIdx.x;
    const int lane = tid & 63;
    const int wave = tid >> 6;
    const int wm = wave >> 1;        // 0..1 (m-half: 128 rows)
    const int wn = wave & 1;         // 0..1 (n-half: 64 cols)

    // bid map: XCD (bid%8) = mt&7 -> the 8 nt-blocks sharing an A-panel co-reside.
    const int bid  = blockIdx.x;     // 0..511
    const int mtlo = bid & 7;
    const int ntb  = (bid >> 3) & 7;
    const int mt   = ((bid >> 6) << 3) | mtlo;

    const char* aT = hws  + (size_t)mt  * NKT * ATB;
    const char* bT = w2ws + (size_t)ntb * NKT * BTB;

    const int l16 = lane & 15;
    const int sl16 = (lane >> 4) * 16;   // 16B k-slot byte offset
    int aoff[8], boff[4];
    #pragma unroll
    for (int i = 0; i < 8; ++i) {
        const int r = wm * 128 + i * 16 + l16;
        aoff[i] = r * 64 + SWZ32(r, sl16);
    }
    #pragma unroll
    for (int j = 0; j < 4; ++j) {
        const int r = wn * 64 + j * 16 + l16;
        boff[j] = r * 64 + SWZ32(r, sl16);
    }

    f32x4 acc[8][4];
    #pragma unroll
    for (int i = 0; i < 8; ++i)
        #pragma unroll
        for (int j = 0; j < 4; ++j)
            acc[i][j] = {0.f, 0.f, 0.f, 0.f};

    // prologue: stage tiles 0,1 into rings 0,1; wait for tile 0
    STAGE_T(0, 0);
    STAGE_T(1, 1);
    asm volatile("s_waitcnt vmcnt(6)" ::: "memory");
    __builtin_amdgcn_sched_barrier(0);
    __builtin_amdgcn_s_barrier();
    __builtin_amdgcn_sched_barrier(0);

    #pragma unroll 1
    for (int t = 0; t < 126; t += 3) {
        TILE(0, t,     1, 6);
        TILE(1, t + 1, 1, 6);
        TILE(2, t + 2, 1, 6);
    }
    TILE(0, 126, 0, 0);   // drain tile 127's loads
    TILE_LAST(1);         // 127 % 3 == 1

    const int orow0 = mt * 256 + wm * 128 + (lane >> 4) * 4;
    const int ocol0 = ntb * 128 + wn * 64 + l16;
    #pragma unroll
    for (int i = 0; i < 8; ++i)
        #pragma unroll
        for (int j = 0; j < 4; ++j)
            #pragma unroll
            for (int jj = 0; jj < 4; ++jj)
                out[(size_t)(orow0 + i * 16 + jj) * N_TOT + (ocol0 + j * 16)] = acc[i][j][jj];
}

// ---------------- fallback: fused single kernel (ws too small) ----------------
__global__ __launch_bounds__(256, 3)
void qffn_fused(const float* __restrict__ x, const float* __restrict__ theta,
                const float* __restrict__ W1, const float* __restrict__ W2,
                float* __restrict__ out)
{
    __shared__ __align__(16) unsigned short sA[128 * 64];
    __shared__ __align__(16) unsigned short sB[128 * 64];

    const int tid  = threadIdx.x;
    const int lane = tid & 63;
    const int wave = tid >> 6;
    const int m0 = blockIdx.x * 128;
    const int n0 = blockIdx.y * 128;

    const int arow = tid & 127;
    float zc[8];
    {
        const float* xp = x + (size_t)(m0 + arow) * 1024;
        f32x4 x0 = *reinterpret_cast<const f32x4*>(xp);
        f32x4 x1 = *reinterpret_cast<const f32x4*>(xp + 4);
        #pragma unroll
        for (int q = 0; q < 4; ++q) {
            zc[q]     = cosf(x0[q]) * cosf(theta[q]);
            zc[q + 4] = cosf(x1[q]) * cosf(theta[q + 4]);
        }
    }

    f32x4 acc[4][4];
    #pragma unroll
    for (int i = 0; i < 4; ++i)
        #pragma unroll
        for (int j = 0; j < 4; ++j)
            acc[i][j] = {0.f, 0.f, 0.f, 0.f};

    const int wr  = (wave >> 1) * 64;
    const int wc  = (wave & 1) * 64;
    const int l16 = lane & 15;
    const int lk8 = (lane >> 4) * 8;

    for (int k0 = 0; k0 < K_TOT; k0 += 64) {
        #pragma unroll
        for (int g = 0; g < 4; ++g) {
            const int cg  = (tid >> 7) + 2 * g;
            const int cgu = __builtin_amdgcn_readfirstlane(cg);
            const float* w1p = W1 + (size_t)(k0 + cgu * 8) * 8;
            i32x4 pk;
            #pragma unroll
            for (int p = 0; p < 4; ++p) {
                float h0 = 0.f, h1 = 0.f;
                #pragma unroll
                for (int q = 0; q < 8; ++q) {
                    h0 = fmaf(zc[q], w1p[(2 * p) * 8 + q], h0);
                    h1 = fmaf(zc[q], w1p[(2 * p + 1) * 8 + q], h1);
                }
                pk[p] = (int)(((unsigned)f2bf(fmaxf(h0, 0.f))) |
                              (((unsigned)f2bf(fmaxf(h1, 0.f))) << 16));
            }
            const int off = (arow * 64 + cg * 8) ^ ((arow & 7) << 3);
            *reinterpret_cast<i32x4*>(&sA[off]) = pk;
        }
        {
            const int fi = tid & 15;
            const int rb = tid >> 4;
            #pragma unroll
            for (int r = 0; r < 8; ++r) {
                const int row = rb + r * 16;
                f32x4 v = *(reinterpret_cast<const f32x4*>(W2 + (size_t)(n0 + row) * K_TOT + k0) + fi);
                unsigned p0 = (unsigned)f2bf(v[0]) | ((unsigned)f2bf(v[1]) << 16);
                unsigned p1 = (unsigned)f2bf(v[2]) | ((unsigned)f2bf(v[3]) << 16);
                const int off = (row * 64 + fi * 4) ^ ((row & 7) << 3);
                *reinterpret_cast<unsigned*>(&sB[off])     = p0;
                *reinterpret_cast<unsigned*>(&sB[off + 2]) = p1;
            }
        }
        __syncthreads();

        #pragma unroll
        for (int s = 0; s < 2; ++s) {
            bf16x8 af2[4], bf2[4];
            #pragma unroll
            for (int i = 0; i < 4; ++i) {
                const int row = wr + i * 16 + l16;
                const int off = (row * 64 + s * 32 + lk8) ^ ((row & 7) << 3);
                af2[i] = *reinterpret_cast<const bf16x8*>(&sA[off]);
            }
            #pragma unroll
            for (int j = 0; j < 4; ++j) {
                const int row = wc + j * 16 + l16;
                const int off = (row * 64 + s * 32 + lk8) ^ ((row & 7) << 3);
                bf2[j] = *reinterpret_cast<const bf16x8*>(&sB[off]);
            }
            #pragma unroll
            for (int i = 0; i < 4; ++i)
                #pragma unroll
                for (int j = 0; j < 4; ++j)
                    acc[i][j] = __builtin_amdgcn_mfma_f32_16x16x32_bf16(af2[i], bf2[j], acc[i][j], 0, 0, 0);
        }
        __syncthreads();
    }

    const int orow0 = m0 + wr + (lane >> 4) * 4;
    const int ocol0 = n0 + wc + l16;
    #pragma unroll
    for (int i = 0; i < 4; ++i)
        #pragma unroll
        for (int j = 0; j < 4; ++j)
            #pragma unroll
            for (int jj = 0; jj < 4; ++jj)
                out[(size_t)(orow0 + i * 16 + jj) * N_TOT + (ocol0 + j * 16)] = acc[i][j][jj];
}

extern "C" void kernel_launch(void* const* d_in, const int* in_sizes, int n_in,
                              void* d_out, int out_size, void* d_ws, size_t ws_size,
                              hipStream_t stream) {
    const float* x     = (const float*)d_in[0];
    const float* theta = (const float*)d_in[1];
    const float* W1    = (const float*)d_in[2];
    const float* W2    = (const float*)d_in[3];
    float* out = (float*)d_out;

    if (ws_size >= WS_NEED) {
        char* hws  = (char*)d_ws;
        char* w2ws = (char*)d_ws + H_BYTES;

        k_prep<<<dim3(4096), dim3(256), 0, stream>>>(x, theta, W1, W2, hws, w2ws);
        k_gemm<<<dim3(512), dim3(256), 0, stream>>>(hws, w2ws, out);
    } else {
        qffn_fused<<<dim3(M_TOT / 128, N_TOT / 128), dim3(256), 0, stream>>>(x, theta, W1, W2, out);
    }
}

// Round 14
// 146.385 us; speedup vs baseline: 1.0120x; 1.0120x over previous
//
#include <hip/hip_runtime.h>
#include <hip/hip_bf16.h>
#include <math.h>

// QuantumFFN: out[m,n] = sum_k relu(sum_q cos(x[m,q])cos(theta[q]) * W1[k,q]) * W2[n,k]
// M=16384, N=1024, K=4096, Q=8.
//
// r14 = r12 champion + 3-group read/MFMA ladder ONLY (stage stays in r12's mid-tile
//   position -- isolates the ladder variable; r13 confounded it with stage-hoist).
// Pass 1 (k_prep): h -> bf16 tiles [mt 64][kt 128][256r][32k], W2 -> [nt 8][kt 128][128r][32k],
//   64-B rows pre-swizzled with SWZ32 (zero conflicts, rounds 3-12).
// Pass 2 (k_gemm): BM=256 BN=128 BK=32, 256 thr (4 waves, wave=128x64), ring-3 LDS
//   (72 KB -> 2 blocks/CU), counted vmcnt(6), 1 barrier per K-tile, XCD map XCD=mt&7.

using f32x4  = __attribute__((ext_vector_type(4))) float;
using bf16x8 = __attribute__((ext_vector_type(8))) short;
using i32x4  = __attribute__((ext_vector_type(4))) int;

#define M_TOT 16384
#define N_TOT 1024
#define K_TOT 4096
#define NKT   128        // K-tiles of 32
#define ATB   16384      // A tile: 256 rows x 32 k x 2B
#define BTB   8192       // B tile: 128 rows x 32 k x 2B

static const size_t H_BYTES   = (size_t)M_TOT * K_TOT * 2;   // 128 MiB
static const size_t W2B_BYTES = (size_t)N_TOT * K_TOT * 2;   //   8 MiB
static const size_t WS_NEED   = H_BYTES + W2B_BYTES;

// swizzle within a 64-byte tile row (4 slots of 16B): slot' = slot ^ ((row>>1)&3)
#define SWZ32(row, bytecol) ((bytecol) ^ ((((row) >> 1) & 3) << 4))

#define GLD16(gp, lp) __builtin_amdgcn_global_load_lds( \
    (const __attribute__((address_space(1))) unsigned int*)(const void*)(gp), \
    (__attribute__((address_space(3))) unsigned int*)(void*)(lp), 16, 0, 0)

static __device__ inline unsigned short f2bf(float f) {
    __hip_bfloat16 b = __float2bfloat16(f);
    unsigned short u;
    __builtin_memcpy(&u, &b, 2);
    return u;
}

// ---------------- pass 1: h and W2 -> bf16 tiles, SWZ32 pre-swizzled ----------------
__global__ __launch_bounds__(256)
void k_prep(const float* __restrict__ x, const float* __restrict__ theta,
            const float* __restrict__ W1, const float* __restrict__ W2,
            char* __restrict__ hws, char* __restrict__ w2ws)
{
    __shared__ float sZ[256 * 8];
    __shared__ float sW[128 * 8];
    const int tid = threadIdx.x;

    if (blockIdx.x < 2048) {
        const int bx = blockIdx.x >> 5;
        const int by = blockIdx.x & 31;

        {   // z for this block's 256 rows (one row per thread)
            const float* xp = x + ((size_t)bx * 256 + tid) * 1024;
            f32x4 a = *reinterpret_cast<const f32x4*>(xp);
            f32x4 b = *reinterpret_cast<const f32x4*>(xp + 4);
            #pragma unroll
            for (int q = 0; q < 4; ++q) {
                sZ[tid * 8 + q]     = cosf(a[q]) * cosf(theta[q]);
                sZ[tid * 8 + 4 + q] = cosf(b[q]) * cosf(theta[q + 4]);
            }
        }
        *reinterpret_cast<f32x4*>(&sW[tid * 4]) =
            *reinterpret_cast<const f32x4*>(W1 + (size_t)by * 1024 + tid * 4);
        __syncthreads();

        const int tm = tid >> 4;     // rows tm*16..+15
        const int tk = tid & 15;     // k-cols tk*8..+7 (within 128-chunk)

        f32x4 wA[8], wB[8];
        #pragma unroll
        for (int kk = 0; kk < 8; ++kk) {
            wA[kk] = *reinterpret_cast<const f32x4*>(&sW[(tk * 8 + kk) * 8]);
            wB[kk] = *reinterpret_cast<const f32x4*>(&sW[(tk * 8 + kk) * 8 + 4]);
        }

        const int kt = by * 4 + (tk >> 2);   // global K-tile (32 k), 0..127
        const int slotb = (tk & 3) * 16;     // 16B slot within 64-B tile row
        char* tb = hws + ((size_t)(bx * NKT + kt)) * ATB;

        #pragma unroll
        for (int i = 0; i < 16; ++i) {
            const int R = tm * 16 + i;       // 0..255
            f32x4 za = *reinterpret_cast<const f32x4*>(&sZ[R * 8]);
            f32x4 zb = *reinterpret_cast<const f32x4*>(&sZ[R * 8 + 4]);
            unsigned hu[8];
            #pragma unroll
            for (int kk = 0; kk < 8; ++kk) {
                float h = 0.f;
                #pragma unroll
                for (int q = 0; q < 4; ++q) {
                    h = fmaf(za[q], wA[kk][q], h);
                    h = fmaf(zb[q], wB[kk][q], h);
                }
                hu[kk] = (unsigned)f2bf(fmaxf(h, 0.f));
            }
            i32x4 pk;
            pk[0] = (int)(hu[0] | (hu[1] << 16));
            pk[1] = (int)(hu[2] | (hu[3] << 16));
            pk[2] = (int)(hu[4] | (hu[5] << 16));
            pk[3] = (int)(hu[6] | (hu[7] << 16));
            *reinterpret_cast<i32x4*>(tb + R * 64 + SWZ32(R, slotb)) = pk;
        }
    } else {
        const int gt = (blockIdx.x - 2048) * 256 + tid;  // one 8-k (16B) unit each
        const int n  = gt >> 9;                          // 512 units per n-row
        const int k8 = gt & 511;
        const float* p = W2 + (size_t)n * K_TOT + k8 * 8;
        f32x4 a = *reinterpret_cast<const f32x4*>(p);
        f32x4 b = *reinterpret_cast<const f32x4*>(p + 4);
        i32x4 pk;
        pk[0] = (int)((unsigned)f2bf(a[0]) | ((unsigned)f2bf(a[1]) << 16));
        pk[1] = (int)((unsigned)f2bf(a[2]) | ((unsigned)f2bf(a[3]) << 16));
        pk[2] = (int)((unsigned)f2bf(b[0]) | ((unsigned)f2bf(b[1]) << 16));
        pk[3] = (int)((unsigned)f2bf(b[2]) | ((unsigned)f2bf(b[3]) << 16));
        const int nt = n >> 7, r = n & 127, kt = k8 >> 2, slotb = (k8 & 3) * 16;
        char* dst = w2ws + ((size_t)(nt * NKT + kt)) * BTB + r * 64 + SWZ32(r, slotb);
        *reinterpret_cast<i32x4*>(dst) = pk;
    }
}

// ---------------- pass 2: out = h @ W2^T ----------------
// ring-3 LDS: slot r at r*24576 (A 16 KB + B 8 KB). Stage tile t+2 mid-tile (r12 position).
// Per tile: reads G1[b0,b1,a0,a1] G2[b2,b3,a2,a3] G3[a4..7] -> stage 6 GLD ->
// lgkm(8) -> 4 MFMA -> lgkm(4) -> 12 MFMA -> lgkm(0) -> 16 MFMA -> vmcnt(6) -> s_barrier.

#define STAGE_T(T, RB2) do {                                              \
    const char* ga_ = aT + (size_t)(T) * ATB;                             \
    const char* gb_ = bT + (size_t)(T) * BTB;                             \
    char* la_ = lds + (RB2) * 24576;                                      \
    GLD16(ga_ + tid * 16,         la_ + tid * 16);                        \
    GLD16(ga_ + 4096 + tid * 16,  la_ + 4096 + tid * 16);                 \
    GLD16(ga_ + 8192 + tid * 16,  la_ + 8192 + tid * 16);                 \
    GLD16(ga_ + 12288 + tid * 16, la_ + 12288 + tid * 16);                \
    GLD16(gb_ + tid * 16,         la_ + 16384 + tid * 16);                \
    GLD16(gb_ + 4096 + tid * 16,  la_ + 16384 + 4096 + tid * 16);         \
} while (0)

#define TILE(RB, T, DOSTAGE, WN) do {                                     \
    const char* sa_ = lds + (RB) * 24576;                                 \
    const char* sb_ = sa_ + 16384;                                        \
    bf16x8 af[8], bfr[4];                                                 \
    /* G1 */                                                              \
    bfr[0] = *reinterpret_cast<const bf16x8*>(sb_ + boff[0]);             \
    bfr[1] = *reinterpret_cast<const bf16x8*>(sb_ + boff[1]);             \
    af[0]  = *reinterpret_cast<const bf16x8*>(sa_ + aoff[0]);             \
    af[1]  = *reinterpret_cast<const bf16x8*>(sa_ + aoff[1]);             \
    __builtin_amdgcn_sched_barrier(0);                                    \
    /* G2 */                                                              \
    bfr[2] = *reinterpret_cast<const bf16x8*>(sb_ + boff[2]);             \
    bfr[3] = *reinterpret_cast<const bf16x8*>(sb_ + boff[3]);             \
    af[2]  = *reinterpret_cast<const bf16x8*>(sa_ + aoff[2]);             \
    af[3]  = *reinterpret_cast<const bf16x8*>(sa_ + aoff[3]);             \
    __builtin_amdgcn_sched_barrier(0);                                    \
    /* G3 */                                                              \
    af[4]  = *reinterpret_cast<const bf16x8*>(sa_ + aoff[4]);             \
    af[5]  = *reinterpret_cast<const bf16x8*>(sa_ + aoff[5]);             \
    af[6]  = *reinterpret_cast<const bf16x8*>(sa_ + aoff[6]);             \
    af[7]  = *reinterpret_cast<const bf16x8*>(sa_ + aoff[7]);             \
    if (DOSTAGE) STAGE_T((T) + 2, ((RB) + 2) % 3);                        \
    asm volatile("s_waitcnt lgkmcnt(8)" ::: "memory");                    \
    __builtin_amdgcn_sched_barrier(0);                                    \
    __builtin_amdgcn_s_setprio(1);                                        \
    _Pragma("unroll")                                                     \
    for (int i = 0; i < 2; ++i)                                           \
        _Pragma("unroll")                                                 \
        for (int j = 0; j < 2; ++j)                                       \
            acc[i][j] = __builtin_amdgcn_mfma_f32_16x16x32_bf16(af[i], bfr[j], acc[i][j], 0, 0, 0); \
    __builtin_amdgcn_s_setprio(0);                                        \
    asm volatile("s_waitcnt lgkmcnt(4)" ::: "memory");                    \
    __builtin_amdgcn_sched_barrier(0);                                    \
    __builtin_amdgcn_s_setprio(1);                                        \
    _Pragma("unroll")                                                     \
    for (int i = 0; i < 2; ++i)                                           \
        _Pragma("unroll")                                                 \
        for (int j = 2; j < 4; ++j)                                       \
            acc[i][j] = __builtin_amdgcn_mfma_f32_16x16x32_bf16(af[i], bfr[j], acc[i][j], 0, 0, 0); \
    _Pragma("unroll")                                                     \
    for (int i = 2; i < 4; ++i)                                           \
        _Pragma("unroll")                                                 \
        for (int j = 0; j < 4; ++j)                                       \
            acc[i][j] = __builtin_amdgcn_mfma_f32_16x16x32_bf16(af[i], bfr[j], acc[i][j], 0, 0, 0); \
    __builtin_amdgcn_s_setprio(0);                                        \
    asm volatile("s_waitcnt lgkmcnt(0)" ::: "memory");                    \
    __builtin_amdgcn_sched_barrier(0);                                    \
    __builtin_amdgcn_s_setprio(1);                                        \
    _Pragma("unroll")                                                     \
    for (int i = 4; i < 8; ++i)                                           \
        _Pragma("unroll")                                                 \
        for (int j = 0; j < 4; ++j)                                       \
            acc[i][j] = __builtin_amdgcn_mfma_f32_16x16x32_bf16(af[i], bfr[j], acc[i][j], 0, 0, 0); \
    __builtin_amdgcn_s_setprio(0);                                        \
    asm volatile("s_waitcnt vmcnt(" #WN ")" ::: "memory");                \
    __builtin_amdgcn_sched_barrier(0);                                    \
    __builtin_amdgcn_s_barrier();                                         \
    __builtin_amdgcn_sched_barrier(0);                                    \
} while (0)

#define TILE_LAST(RB) do {                                                \
    const char* sa_ = lds + (RB) * 24576;                                 \
    const char* sb_ = sa_ + 16384;                                        \
    bf16x8 af[8], bfr[4];                                                 \
    _Pragma("unroll")                                                     \
    for (int i = 0; i < 8; ++i)                                           \
        af[i] = *reinterpret_cast<const bf16x8*>(sa_ + aoff[i]);          \
    _Pragma("unroll")                                                     \
    for (int j = 0; j < 4; ++j)                                           \
        bfr[j] = *reinterpret_cast<const bf16x8*>(sb_ + boff[j]);         \
    asm volatile("s_waitcnt lgkmcnt(0)" ::: "memory");                    \
    __builtin_amdgcn_sched_barrier(0);                                    \
    _Pragma("unroll")                                                     \
    for (int i = 0; i < 8; ++i)                                           \
        _Pragma("unroll")                                                 \
        for (int j = 0; j < 4; ++j)                                       \
            acc[i][j] = __builtin_amdgcn_mfma_f32_16x16x32_bf16(af[i], bfr[j], acc[i][j], 0, 0, 0); \
} while (0)

__global__ __launch_bounds__(256, 2)
void k_gemm(const char* __restrict__ hws, const char* __restrict__ w2ws,
            float* __restrict__ out)
{
    __shared__ __align__(16) char lds[73728];   // 3 x (16K A + 8K B)

    const int tid  = threadIdx.x;
    const int lane = tid & 63;
    const int wave = tid >> 6;
    const int wm = wave >> 1;        // 0..1 (m-half: 128 rows)
    const int wn = wave & 1;         // 0..1 (n-half: 64 cols)

    // bid map: XCD (bid%8) = mt&7 -> the 8 nt-blocks sharing an A-panel co-reside.
    const int bid  = blockIdx.x;     // 0..511
    const int mtlo = bid & 7;
    const int ntb  = (bid >> 3) & 7;
    const int mt   = ((bid >> 6) << 3) | mtlo;

    const char* aT = hws  + (size_t)mt  * NKT * ATB;
    const char* bT = w2ws + (size_t)ntb * NKT * BTB;

    const int l16 = lane & 15;
    const int sl16 = (lane >> 4) * 16;   // 16B k-slot byte offset
    int aoff[8], boff[4];
    #pragma unroll
    for (int i = 0; i < 8; ++i) {
        const int r = wm * 128 + i * 16 + l16;
        aoff[i] = r * 64 + SWZ32(r, sl16);
    }
    #pragma unroll
    for (int j = 0; j < 4; ++j) {
        const int r = wn * 64 + j * 16 + l16;
        boff[j] = r * 64 + SWZ32(r, sl16);
    }

    f32x4 acc[8][4];
    #pragma unroll
    for (int i = 0; i < 8; ++i)
        #pragma unroll
        for (int j = 0; j < 4; ++j)
            acc[i][j] = {0.f, 0.f, 0.f, 0.f};

    // prologue: stage tiles 0,1 into rings 0,1; wait for tile 0
    STAGE_T(0, 0);
    STAGE_T(1, 1);
    asm volatile("s_waitcnt vmcnt(6)" ::: "memory");
    __builtin_amdgcn_sched_barrier(0);
    __builtin_amdgcn_s_barrier();
    __builtin_amdgcn_sched_barrier(0);

    #pragma unroll 1
    for (int t = 0; t < 126; t += 3) {
        TILE(0, t,     1, 6);
        TILE(1, t + 1, 1, 6);
        TILE(2, t + 2, 1, 6);
    }
    TILE(0, 126, 0, 0);   // drain tile 127's loads
    TILE_LAST(1);         // 127 % 3 == 1

    const int orow0 = mt * 256 + wm * 128 + (lane >> 4) * 4;
    const int ocol0 = ntb * 128 + wn * 64 + l16;
    #pragma unroll
    for (int i = 0; i < 8; ++i)
        #pragma unroll
        for (int j = 0; j < 4; ++j)
            #pragma unroll
            for (int jj = 0; jj < 4; ++jj)
                out[(size_t)(orow0 + i * 16 + jj) * N_TOT + (ocol0 + j * 16)] = acc[i][j][jj];
}

// ---------------- fallback: fused single kernel (ws too small) ----------------
__global__ __launch_bounds__(256, 3)
void qffn_fused(const float* __restrict__ x, const float* __restrict__ theta,
                const float* __restrict__ W1, const float* __restrict__ W2,
                float* __restrict__ out)
{
    __shared__ __align__(16) unsigned short sA[128 * 64];
    __shared__ __align__(16) unsigned short sB[128 * 64];

    const int tid  = threadIdx.x;
    const int lane = tid & 63;
    const int wave = tid >> 6;
    const int m0 = blockIdx.x * 128;
    const int n0 = blockIdx.y * 128;

    const int arow = tid & 127;
    float zc[8];
    {
        const float* xp = x + (size_t)(m0 + arow) * 1024;
        f32x4 x0 = *reinterpret_cast<const f32x4*>(xp);
        f32x4 x1 = *reinterpret_cast<const f32x4*>(xp + 4);
        #pragma unroll
        for (int q = 0; q < 4; ++q) {
            zc[q]     = cosf(x0[q]) * cosf(theta[q]);
            zc[q + 4] = cosf(x1[q]) * cosf(theta[q + 4]);
        }
    }

    f32x4 acc[4][4];
    #pragma unroll
    for (int i = 0; i < 4; ++i)
        #pragma unroll
        for (int j = 0; j < 4; ++j)
            acc[i][j] = {0.f, 0.f, 0.f, 0.f};

    const int wr  = (wave >> 1) * 64;
    const int wc  = (wave & 1) * 64;
    const int l16 = lane & 15;
    const int lk8 = (lane >> 4) * 8;

    for (int k0 = 0; k0 < K_TOT; k0 += 64) {
        #pragma unroll
        for (int g = 0; g < 4; ++g) {
            const int cg  = (tid >> 7) + 2 * g;
            const int cgu = __builtin_amdgcn_readfirstlane(cg);
            const float* w1p = W1 + (size_t)(k0 + cgu * 8) * 8;
            i32x4 pk;
            #pragma unroll
            for (int p = 0; p < 4; ++p) {
                float h0 = 0.f, h1 = 0.f;
                #pragma unroll
                for (int q = 0; q < 8; ++q) {
                    h0 = fmaf(zc[q], w1p[(2 * p) * 8 + q], h0);
                    h1 = fmaf(zc[q], w1p[(2 * p + 1) * 8 + q], h1);
                }
                pk[p] = (int)(((unsigned)f2bf(fmaxf(h0, 0.f))) |
                              (((unsigned)f2bf(fmaxf(h1, 0.f))) << 16));
            }
            const int off = (arow * 64 + cg * 8) ^ ((arow & 7) << 3);
            *reinterpret_cast<i32x4*>(&sA[off]) = pk;
        }
        {
            const int fi = tid & 15;
            const int rb = tid >> 4;
            #pragma unroll
            for (int r = 0; r < 8; ++r) {
                const int row = rb + r * 16;
                f32x4 v = *(reinterpret_cast<const f32x4*>(W2 + (size_t)(n0 + row) * K_TOT + k0) + fi);
                unsigned p0 = (unsigned)f2bf(v[0]) | ((unsigned)f2bf(v[1]) << 16);
                unsigned p1 = (unsigned)f2bf(v[2]) | ((unsigned)f2bf(v[3]) << 16);
                const int off = (row * 64 + fi * 4) ^ ((row & 7) << 3);
                *reinterpret_cast<unsigned*>(&sB[off])     = p0;
                *reinterpret_cast<unsigned*>(&sB[off + 2]) = p1;
            }
        }
        __syncthreads();

        #pragma unroll
        for (int s = 0; s < 2; ++s) {
            bf16x8 af2[4], bf2[4];
            #pragma unroll
            for (int i = 0; i < 4; ++i) {
                const int row = wr + i * 16 + l16;
                const int off = (row * 64 + s * 32 + lk8) ^ ((row & 7) << 3);
                af2[i] = *reinterpret_cast<const bf16x8*>(&sA[off]);
            }
            #pragma unroll
            for (int j = 0; j < 4; ++j) {
                const int row = wc + j * 16 + l16;
                const int off = (row * 64 + s * 32 + lk8) ^ ((row & 7) << 3);
                bf2[j] = *reinterpret_cast<const bf16x8*>(&sB[off]);
            }
            #pragma unroll
            for (int i = 0; i < 4; ++i)
                #pragma unroll
                for (int j = 0; j < 4; ++j)
                    acc[i][j] = __builtin_amdgcn_mfma_f32_16x16x32_bf16(af2[i], bf2[j], acc[i][j], 0, 0, 0);
        }
        __syncthreads();
    }

    const int orow0 = m0 + wr + (lane >> 4) * 4;
    const int ocol0 = n0 + wc + l16;
    #pragma unroll
    for (int i = 0; i < 4; ++i)
        #pragma unroll
        for (int j = 0; j < 4; ++j)
            #pragma unroll
            for (int jj = 0; jj < 4; ++jj)
                out[(size_t)(orow0 + i * 16 + jj) * N_TOT + (ocol0 + j * 16)] = acc[i][j][jj];
}

extern "C" void kernel_launch(void* const* d_in, const int* in_sizes, int n_in,
                              void* d_out, int out_size, void* d_ws, size_t ws_size,
                              hipStream_t stream) {
    const float* x     = (const float*)d_in[0];
    const float* theta = (const float*)d_in[1];
    const float* W1    = (const float*)d_in[2];
    const float* W2    = (const float*)d_in[3];
    float* out = (float*)d_out;

    if (ws_size >= WS_NEED) {
        char* hws  = (char*)d_ws;
        char* w2ws = (char*)d_ws + H_BYTES;

        k_prep<<<dim3(4096), dim3(256), 0, stream>>>(x, theta, W1, W2, hws, w2ws);
        k_gemm<<<dim3(512), dim3(256), 0, stream>>>(hws, w2ws, out);
    } else {
        qffn_fused<<<dim3(M_TOT / 128, N_TOT / 128), dim3(256), 0, stream>>>(x, theta, W1, W2, out);
    }
}